// Round 1
// baseline (167.297 us; speedup 1.0000x reference)
//
#include <hip/hip_runtime.h>

typedef unsigned int u32;
typedef unsigned short u16;

#define B_   2
#define CIN  256
#define COUT 256
#define PD   34
#define PLANE (PD*PD)        // 1156
#define P3   (PD*PD*PD)      // 39304
#define SPAT 32768           // 32*32*32

#define XT_ELEMS ((size_t)B_ * P3 * CIN)   // 20,123,648
#define XT_BYTES (XT_ELEMS * 2)            // 40,247,296
#define WB_OFF_BYTES XT_BYTES

typedef __attribute__((ext_vector_type(8))) short bf16x8;
typedef __attribute__((ext_vector_type(8))) u16  u16x8;
typedef __attribute__((ext_vector_type(4))) float f32x4;

__device__ __forceinline__ u16 f2bf(float f) {
  union { float f; u32 u; } v; v.f = f;
  u32 r = v.u + 0x7FFFu + ((v.u >> 16) & 1u);   // RNE
  return (u16)(r >> 16);
}

__device__ __forceinline__ void gload_lds16(const void* g, void* l) {
  __builtin_amdgcn_global_load_lds(
      (const __attribute__((address_space(1))) u32*)g,
      (__attribute__((address_space(3))) u32*)l,
      16, 0, 0);
}

// ---------------- W fp32 -> bf16 (layout unchanged: [7*COUT][CIN]) ----------
__global__ void convert_w(const float* __restrict__ W, u16* __restrict__ wb) {
  u32 idx = (blockIdx.x * 256u + threadIdx.x) * 8u;   // 224 blocks * 256 * 8 = 458752
  float4 f0 = ((const float4*)(W + idx))[0];
  float4 f1 = ((const float4*)(W + idx))[1];
  u16x8 v;
  v[0] = f2bf(f0.x); v[1] = f2bf(f0.y); v[2] = f2bf(f0.z); v[3] = f2bf(f0.w);
  v[4] = f2bf(f1.x); v[5] = f2bf(f1.y); v[6] = f2bf(f1.z); v[7] = f2bf(f1.w);
  *(u16x8*)(wb + idx) = v;
}

// ------- x (b,i,t,r,c) fp32 -> padded k-major bf16 x_t[b][p][i] -------------
// one workgroup per (b,t,r) row; border stays zero from the memset.
__global__ void transpose_pad(const float* __restrict__ x, u16* __restrict__ xt) {
  __shared__ __align__(16) u16 tile[32][256];
  u32 wg = blockIdx.x;                       // 2048 = B*32*32
  u32 b = wg >> 10, t = (wg >> 5) & 31, r = wg & 31;
  u32 i = threadIdx.x;                       // channel
  const float* src = x + ((size_t)(b * CIN + i) * SPAT + t * 1024u + r * 32u);
#pragma unroll
  for (int q = 0; q < 8; ++q) {
    float4 f = ((const float4*)src)[q];
    tile[q * 4 + 0][i] = f2bf(f.x);
    tile[q * 4 + 1][i] = f2bf(f.y);
    tile[q * 4 + 2][i] = f2bf(f.z);
    tile[q * 4 + 3][i] = f2bf(f.w);
  }
  __syncthreads();
  u32 c = threadIdx.x >> 3, chunk = threadIdx.x & 7;
  size_t p = (size_t)b * P3 + (size_t)((t + 1) * PD + (r + 1)) * PD + 1 + c;
  uint4* dst = (uint4*)(xt + p * CIN + chunk * 32u);
  const uint4* s = (const uint4*)&tile[c][chunk * 32u];
  dst[0] = s[0]; dst[1] = s[1]; dst[2] = s[2]; dst[3] = s[3];
}

// ---------------- main fused stencil-GEMM -----------------------------------
// grid 1024: 2 cout-halves x 512 spatial tiles (tile = 1 t-plane, 4 r-rows, 32 c)
__global__ __launch_bounds__(256, 4)
void conv_main(const u16* __restrict__ xt, const u16* __restrict__ wb,
               float* __restrict__ out) {
  __shared__ __align__(16) u16 ldsA[4096];   // [kb(4)][m(128)][8]
  __shared__ __align__(16) u16 ldsB[4096];   // [kb(4)][n(128)][8]

  u32 bid = blockIdx.x;
  u32 id2 = (bid & 7) * 128u + (bid >> 3);   // XCD swizzle (1024 % 8 == 0)
  u32 st  = id2 >> 1;
  u32 ch  = id2 & 1;
  u32 b   = st >> 8;
  u32 t   = (st >> 3) & 31;
  u32 r0  = (st & 7) * 4u;
  u32 coutBase = ch * 128u;

  u32 tid = threadIdx.x;
  u32 lane = tid & 63, wave = tid >> 6;
  u32 wm = wave >> 1, wn = wave & 1;

  u32 pCenter = ((t + 1) * PD + (r0 + 1)) * PD + 1;
  const u16* xb = xt + (size_t)b * P3 * CIN;

  // staging indices: wave w stages kb = w; q in {0,1} covers rows 0-63 / 64-127
  u32 n0 = lane, n1 = 64u + lane;
  u32 pc0 = pCenter + (n0 >> 5) * PD + (n0 & 31);
  u32 pc1 = pCenter + (n1 >> 5) * PD + (n1 & 31);
  u16* lA0 = &ldsA[(wave * 2 + 0) * 512];
  u16* lA1 = &ldsA[(wave * 2 + 1) * 512];
  u16* lB0 = &ldsB[(wave * 2 + 0) * 512];
  u16* lB1 = &ldsB[(wave * 2 + 1) * 512];

  f32x4 acc[4][4];
#pragma unroll
  for (int i = 0; i < 4; ++i)
#pragma unroll
    for (int j = 0; j < 4; ++j) acc[i][j] = (f32x4)0.0f;

  const u16* ldsAr = &ldsA[(lane >> 4) * 1024 + (wm * 64 + (lane & 15)) * 8];
  const u16* ldsBr = &ldsB[(lane >> 4) * 1024 + (wn * 64 + (lane & 15)) * 8];

  for (int d = 0; d < 7; ++d) {
    int off = (d == 1) ? -PLANE : (d == 2) ? PLANE
            : (d == 3) ? -PD    : (d == 4) ? PD
            : (d == 5) ? -1     : (d == 6) ? 1 : 0;
    u32 wrowBase = (u32)d * COUT + coutBase;
    const u16* ga0 = wb + (size_t)(wrowBase + n0) * CIN + wave * 8u;
    const u16* ga1 = wb + (size_t)(wrowBase + n1) * CIN + wave * 8u;
    const u16* gb0 = xb + (size_t)((int)pc0 + off) * CIN + wave * 8u;
    const u16* gb1 = xb + (size_t)((int)pc1 + off) * CIN + wave * 8u;

    for (int kc = 0; kc < 256; kc += 32) {
      gload_lds16(ga0 + kc, lA0);
      gload_lds16(ga1 + kc, lA1);
      gload_lds16(gb0 + kc, lB0);
      gload_lds16(gb1 + kc, lB1);

      __syncthreads();   // compiler drains vmcnt(0) before s_barrier

      bf16x8 a0 = *(const bf16x8*)(ldsAr);
      bf16x8 a1 = *(const bf16x8*)(ldsAr + 128);
      bf16x8 a2 = *(const bf16x8*)(ldsAr + 256);
      bf16x8 a3 = *(const bf16x8*)(ldsAr + 384);
      bf16x8 b0 = *(const bf16x8*)(ldsBr);
      bf16x8 b1 = *(const bf16x8*)(ldsBr + 128);
      bf16x8 b2 = *(const bf16x8*)(ldsBr + 256);
      bf16x8 b3 = *(const bf16x8*)(ldsBr + 384);

      acc[0][0] = __builtin_amdgcn_mfma_f32_16x16x32_bf16(a0, b0, acc[0][0], 0, 0, 0);
      acc[0][1] = __builtin_amdgcn_mfma_f32_16x16x32_bf16(a0, b1, acc[0][1], 0, 0, 0);
      acc[0][2] = __builtin_amdgcn_mfma_f32_16x16x32_bf16(a0, b2, acc[0][2], 0, 0, 0);
      acc[0][3] = __builtin_amdgcn_mfma_f32_16x16x32_bf16(a0, b3, acc[0][3], 0, 0, 0);
      acc[1][0] = __builtin_amdgcn_mfma_f32_16x16x32_bf16(a1, b0, acc[1][0], 0, 0, 0);
      acc[1][1] = __builtin_amdgcn_mfma_f32_16x16x32_bf16(a1, b1, acc[1][1], 0, 0, 0);
      acc[1][2] = __builtin_amdgcn_mfma_f32_16x16x32_bf16(a1, b2, acc[1][2], 0, 0, 0);
      acc[1][3] = __builtin_amdgcn_mfma_f32_16x16x32_bf16(a1, b3, acc[1][3], 0, 0, 0);
      acc[2][0] = __builtin_amdgcn_mfma_f32_16x16x32_bf16(a2, b0, acc[2][0], 0, 0, 0);
      acc[2][1] = __builtin_amdgcn_mfma_f32_16x16x32_bf16(a2, b1, acc[2][1], 0, 0, 0);
      acc[2][2] = __builtin_amdgcn_mfma_f32_16x16x32_bf16(a2, b2, acc[2][2], 0, 0, 0);
      acc[2][3] = __builtin_amdgcn_mfma_f32_16x16x32_bf16(a2, b3, acc[2][3], 0, 0, 0);
      acc[3][0] = __builtin_amdgcn_mfma_f32_16x16x32_bf16(a3, b0, acc[3][0], 0, 0, 0);
      acc[3][1] = __builtin_amdgcn_mfma_f32_16x16x32_bf16(a3, b1, acc[3][1], 0, 0, 0);
      acc[3][2] = __builtin_amdgcn_mfma_f32_16x16x32_bf16(a3, b2, acc[3][2], 0, 0, 0);
      acc[3][3] = __builtin_amdgcn_mfma_f32_16x16x32_bf16(a3, b3, acc[3][3], 0, 0, 0);

      __syncthreads();   // protect LDS before next staging
    }
  }

  // epilogue: D row = (lane>>4)*4 + reg (cout), col = lane&15 (spatial)
  u32 rowg = (lane >> 4) * 4u;
  u32 coln = lane & 15u;
  u32 sOutBase = t * 1024u + r0 * 32u;
  float* ob = out + (size_t)(b * COUT + coutBase + wm * 64u) * SPAT
                  + sOutBase + wn * 64u + coln;
#pragma unroll
  for (int mi = 0; mi < 4; ++mi)
#pragma unroll
    for (int ni = 0; ni < 4; ++ni) {
      f32x4 v = acc[mi][ni];
#pragma unroll
      for (int rg = 0; rg < 4; ++rg)
        ob[(size_t)(mi * 16 + rowg + rg) * SPAT + ni * 16] = v[rg];
    }
}

extern "C" void kernel_launch(void* const* d_in, const int* in_sizes, int n_in,
                              void* d_out, int out_size, void* d_ws, size_t ws_size,
                              hipStream_t stream) {
  const float* x = (const float*)d_in[0];
  const float* W = (const float*)d_in[1];
  float* out = (float*)d_out;
  u16* xt  = (u16*)d_ws;
  u16* wbf = (u16*)((char*)d_ws + WB_OFF_BYTES);

  // zero whole padded x_t (border stays zero; interior overwritten below)
  hipMemsetAsync(d_ws, 0, XT_BYTES, stream);
  hipLaunchKernelGGL(convert_w,     dim3(224),  dim3(256), 0, stream, W, wbf);
  hipLaunchKernelGGL(transpose_pad, dim3(2048), dim3(256), 0, stream, x, xt);
  hipLaunchKernelGGL(conv_main,     dim3(1024), dim3(256), 0, stream, xt, wbf, out);
}

// Round 2
// 138.292 us; speedup vs baseline: 1.2097x; 1.2097x over previous
//
#include <hip/hip_runtime.h>

typedef unsigned int u32;
typedef unsigned short u16;

#define B_   2
#define CIN  256
#define COUT 256
#define PD   34
#define PLANE (PD*PD)        // 1156
#define P3   (PD*PD*PD)      // 39304
#define SPAT 32768           // 32*32*32

#define XT_ELEMS ((size_t)B_ * P3 * CIN)   // 20,123,648
#define XT_BYTES (XT_ELEMS * 2)            // 40,247,296
#define WB_OFF_BYTES XT_BYTES

typedef __attribute__((ext_vector_type(8))) short bf16x8;
typedef __attribute__((ext_vector_type(8))) u16  u16x8;
typedef __attribute__((ext_vector_type(4))) float f32x4;

__device__ __forceinline__ u16 f2bf(float f) {
  union { float f; u32 u; } v; v.f = f;
  u32 r = v.u + 0x7FFFu + ((v.u >> 16) & 1u);   // RNE
  return (u16)(r >> 16);
}

__device__ __forceinline__ void gload_lds16(const void* g, void* l) {
  __builtin_amdgcn_global_load_lds(
      (const __attribute__((address_space(1))) u32*)g,
      (__attribute__((address_space(3))) u32*)l,
      16, 0, 0);
}

// ---------------- W fp32 -> bf16 (layout unchanged: [7*COUT][CIN]) ----------
__global__ void convert_w(const float* __restrict__ W, u16* __restrict__ wb) {
  u32 idx = (blockIdx.x * 256u + threadIdx.x) * 8u;   // 224 blocks
  float4 f0 = ((const float4*)(W + idx))[0];
  float4 f1 = ((const float4*)(W + idx))[1];
  u16x8 v;
  v[0] = f2bf(f0.x); v[1] = f2bf(f0.y); v[2] = f2bf(f0.z); v[3] = f2bf(f0.w);
  v[4] = f2bf(f1.x); v[5] = f2bf(f1.y); v[6] = f2bf(f1.z); v[7] = f2bf(f1.w);
  *(u16x8*)(wb + idx) = v;
}

// ------- x (b,i,t,r,c) fp32 -> padded k-major bf16 x_t[b][p][i] -------------
__global__ void transpose_pad(const float* __restrict__ x, u16* __restrict__ xt) {
  __shared__ __align__(16) u16 tile[32][256];
  u32 wg = blockIdx.x;                       // 2048 = B*32*32
  u32 b = wg >> 10, t = (wg >> 5) & 31, r = wg & 31;
  u32 i = threadIdx.x;                       // channel
  const float* src = x + ((size_t)(b * CIN + i) * SPAT + t * 1024u + r * 32u);
#pragma unroll
  for (int q = 0; q < 8; ++q) {
    float4 f = ((const float4*)src)[q];
    tile[q * 4 + 0][i] = f2bf(f.x);
    tile[q * 4 + 1][i] = f2bf(f.y);
    tile[q * 4 + 2][i] = f2bf(f.z);
    tile[q * 4 + 3][i] = f2bf(f.w);
  }
  __syncthreads();
  u32 c = threadIdx.x >> 3, chunk = threadIdx.x & 7;
  size_t p = (size_t)b * P3 + (size_t)((t + 1) * PD + (r + 1)) * PD + 1 + c;
  uint4* dst = (uint4*)(xt + p * CIN + chunk * 32u);
  const uint4* s = (const uint4*)&tile[c][chunk * 32u];
  dst[0] = s[0]; dst[1] = s[1]; dst[2] = s[2]; dst[3] = s[3];
}

// ---------------- main fused stencil-GEMM (2-phase dbuf, 8 waves) -----------
// grid 256 (= 1 block/CU): tile = 256 cout x 256 spatial (1 t-plane, 8 r, 32 c)
// K = 7 taps x 256 cin, BK = 64 -> 28 K-steps, 64 MFMA/wave/step, 1 barrier/step
__global__ __launch_bounds__(512, 2)
void conv_main(const u16* __restrict__ xt, const u16* __restrict__ wb,
               float* __restrict__ out) {
  // [buf][A=0/B=1][kb(8)][row(256)][8 k-elems]  = 128 KiB
  __shared__ __align__(16) u16 lds[2][2][8][256][8];

  u32 bid = blockIdx.x;
  u32 id2 = (bid & 7) * 32u + (bid >> 3);    // XCD swizzle (256 % 8 == 0)
  u32 b  = id2 >> 7;
  u32 t  = (id2 >> 2) & 31;
  u32 r0 = (id2 & 3) * 8u;

  u32 tid = threadIdx.x;
  u32 lane = tid & 63, wave = tid >> 6;
  u32 wm = wave >> 2, wn = wave & 3;         // 2 x 4 wave grid

  const u16* xb = xt + (size_t)b * P3 * CIN;
  u32 pBase = ((t + 1) * PD + (r0 + 1)) * PD + 1;

  // per-thread staging offsets (element units); chunk i covers rows i*64..+63
  u32 aOff[4], bOff[4];
#pragma unroll
  for (int i = 0; i < 4; ++i) {
    u32 n = i * 64u + lane;
    aOff[i] = n * CIN + wave * 8u;
    bOff[i] = (pBase + (n >> 5) * PD + (n & 31)) * CIN + wave * 8u;
  }

#define STAGE(BUF, KT) do {                                                  \
    u32 d_  = (u32)(KT) >> 2;                                                \
    u32 kc_ = ((u32)(KT) & 3u) * 64u;                                        \
    int off_ = (d_ == 1) ? -PLANE : (d_ == 2) ? PLANE                        \
             : (d_ == 3) ? -PD    : (d_ == 4) ? PD                           \
             : (d_ == 5) ? -1     : (d_ == 6) ? 1 : 0;                       \
    const u16* gA_ = wb + (size_t)d_ * (COUT * CIN) + kc_;                   \
    const u16* gB_ = xb + (ptrdiff_t)((int)kc_ + off_ * CIN);                \
    _Pragma("unroll")                                                        \
    for (int i_ = 0; i_ < 4; ++i_) {                                         \
      gload_lds16(gA_ + aOff[i_], &lds[BUF][0][wave][i_ * 64][0]);           \
      gload_lds16(gB_ + bOff[i_], &lds[BUF][1][wave][i_ * 64][0]);           \
    }                                                                        \
  } while (0)

  f32x4 acc[8][4];
#pragma unroll
  for (int i = 0; i < 8; ++i)
#pragma unroll
    for (int j = 0; j < 4; ++j) acc[i][j] = (f32x4)0.0f;

#define COMPUTE(BUF) do {                                                    \
    const u16* pA_ = &lds[BUF][0][lane >> 4][wm * 128 + (lane & 15)][0];     \
    const u16* pB_ = &lds[BUF][1][lane >> 4][wn * 64 + (lane & 15)][0];      \
    _Pragma("unroll")                                                        \
    for (int ks = 0; ks < 2; ++ks) {                                         \
      bf16x8 af[8], bv[4];                                                   \
      _Pragma("unroll")                                                      \
      for (int mi = 0; mi < 8; ++mi)                                         \
        af[mi] = *(const bf16x8*)(pA_ + ks * 8192 + mi * 128);               \
      _Pragma("unroll")                                                      \
      for (int ni = 0; ni < 4; ++ni)                                         \
        bv[ni] = *(const bf16x8*)(pB_ + ks * 8192 + ni * 128);               \
      _Pragma("unroll")                                                      \
      for (int mi = 0; mi < 8; ++mi)                                         \
        _Pragma("unroll")                                                    \
        for (int ni = 0; ni < 4; ++ni)                                       \
          acc[mi][ni] = __builtin_amdgcn_mfma_f32_16x16x32_bf16(             \
              af[mi], bv[ni], acc[mi][ni], 0, 0, 0);                         \
    }                                                                        \
  } while (0)

  STAGE(0, 0);
  __syncthreads();

#pragma unroll 1
  for (int kt2 = 0; kt2 < 14; ++kt2) {
    int kt = kt2 * 2;
    STAGE(1, kt + 1);        // prefetch next into buf1
    COMPUTE(0);
    __syncthreads();         // drains vmcnt(0): buf1 ready, buf0 free
    if (kt + 2 < 28) STAGE(0, kt + 2);
    COMPUTE(1);
    __syncthreads();
  }

#undef STAGE
#undef COMPUTE

  // epilogue: D row = (lane>>4)*4 + reg (cout), col = lane&15 (spatial)
  u32 rowg = (lane >> 4) * 4u;
  u32 coln = lane & 15u;
  float* ob = out + (size_t)(b * COUT + wm * 128u) * SPAT + t * 1024u + r0 * 32u;
#pragma unroll
  for (int mi = 0; mi < 8; ++mi)
#pragma unroll
    for (int ni = 0; ni < 4; ++ni) {
      f32x4 v = acc[mi][ni];
      u32 n = wn * 64u + ni * 16u + coln;    // spatial within contiguous 256-span
#pragma unroll
      for (int rg = 0; rg < 4; ++rg)
        ob[(size_t)(mi * 16u + rowg + rg) * SPAT + n] = v[rg];
    }
}

extern "C" void kernel_launch(void* const* d_in, const int* in_sizes, int n_in,
                              void* d_out, int out_size, void* d_ws, size_t ws_size,
                              hipStream_t stream) {
  const float* x = (const float*)d_in[0];
  const float* W = (const float*)d_in[1];
  float* out = (float*)d_out;
  u16* xt  = (u16*)d_ws;
  u16* wbf = (u16*)((char*)d_ws + WB_OFF_BYTES);

  hipMemsetAsync(d_ws, 0, XT_BYTES, stream);
  hipLaunchKernelGGL(convert_w,     dim3(224),  dim3(256), 0, stream, W, wbf);
  hipLaunchKernelGGL(transpose_pad, dim3(2048), dim3(256), 0, stream, x, xt);
  hipLaunchKernelGGL(conv_main,     dim3(256),  dim3(512), 0, stream, xt, wbf, out);
}

// Round 3
// 125.689 us; speedup vs baseline: 1.3310x; 1.1003x over previous
//
#include <hip/hip_runtime.h>

typedef unsigned int u32;
typedef unsigned short u16;

#define B_   2
#define CIN  256
#define COUT 256
#define PD   34
#define PLANE (PD*PD)        // 1156
#define P3   (PD*PD*PD)      // 39304
#define SPAT 32768           // 32*32*32

#define XT_ELEMS ((size_t)B_ * P3 * CIN)
#define XT_BYTES (XT_ELEMS * 2)
#define WB_OFF_BYTES XT_BYTES

typedef __attribute__((ext_vector_type(8))) short bf16x8;
typedef __attribute__((ext_vector_type(8))) u16  u16x8;
typedef __attribute__((ext_vector_type(4))) float f32x4;

__device__ __forceinline__ u16 f2bf(float f) {
  union { float f; u32 u; } v; v.f = f;
  u32 r = v.u + 0x7FFFu + ((v.u >> 16) & 1u);   // RNE
  return (u16)(r >> 16);
}

__device__ __forceinline__ void gload_lds16(const void* g, void* l) {
  __builtin_amdgcn_global_load_lds(
      (const __attribute__((address_space(1))) u32*)g,
      (__attribute__((address_space(3))) u32*)l,
      16, 0, 0);
}

__device__ __forceinline__ int tapOff(u32 d) {
  return (d == 1) ? -PLANE : (d == 2) ? PLANE
       : (d == 3) ? -PD    : (d == 4) ? PD
       : (d == 5) ? -1     : (d == 6) ? 1 : 0;
}

// ---------------- W fp32 -> bf16 --------------------------------------------
__global__ void convert_w(const float* __restrict__ W, u16* __restrict__ wb) {
  u32 idx = (blockIdx.x * 256u + threadIdx.x) * 8u;
  float4 f0 = ((const float4*)(W + idx))[0];
  float4 f1 = ((const float4*)(W + idx))[1];
  u16x8 v;
  v[0] = f2bf(f0.x); v[1] = f2bf(f0.y); v[2] = f2bf(f0.z); v[3] = f2bf(f0.w);
  v[4] = f2bf(f1.x); v[5] = f2bf(f1.y); v[6] = f2bf(f1.z); v[7] = f2bf(f1.w);
  *(u16x8*)(wb + idx) = v;
}

// ------- x (b,i,t,r,c) fp32 -> padded k-major bf16 x_t[b][p][i] -------------
__global__ void transpose_pad(const float* __restrict__ x, u16* __restrict__ xt) {
  __shared__ __align__(16) u16 tile[32][256];
  u32 wg = blockIdx.x;                       // 2048 = B*32*32
  u32 b = wg >> 10, t = (wg >> 5) & 31, r = wg & 31;
  u32 i = threadIdx.x;
  const float* src = x + ((size_t)(b * CIN + i) * SPAT + t * 1024u + r * 32u);
#pragma unroll
  for (int q = 0; q < 8; ++q) {
    float4 f = ((const float4*)src)[q];
    tile[q * 4 + 0][i] = f2bf(f.x);
    tile[q * 4 + 1][i] = f2bf(f.y);
    tile[q * 4 + 2][i] = f2bf(f.z);
    tile[q * 4 + 3][i] = f2bf(f.w);
  }
  __syncthreads();
  u32 c = threadIdx.x >> 3, chunk = threadIdx.x & 7;
  size_t p = (size_t)b * P3 + (size_t)((t + 1) * PD + (r + 1)) * PD + 1 + c;
  uint4* dst = (uint4*)(xt + p * CIN + chunk * 32u);
  const uint4* s = (const uint4*)&tile[c][chunk * 32u];
  dst[0] = s[0]; dst[1] = s[1]; dst[2] = s[2]; dst[3] = s[3];
}

// ---------------- main: 8-wave 256x256 tile, 4-phase counted-vmcnt schedule -
// K = 7 taps x 256 = 28 K-tiles of BK=64. Per tile: 4 phases (one C-quadrant,
// 16 MFMA each), 2 global_load_lds per phase staging 6 units (3 phases) ahead,
// ONE s_waitcnt vmcnt(4) per tile (drain-0 only in the tail).
__global__ __launch_bounds__(512, 2)
void conv_main(const u16* __restrict__ xt, const u16* __restrict__ wb,
               float* __restrict__ out) {
  // [buf][A=0/B=1][kb(8)][row/slot(256)][8]  = 128 KiB
  __shared__ __align__(16) u16 lds[2][2][8][256][8];

  u32 bid = blockIdx.x;
  u32 id2 = (bid & 7) * 32u + (bid >> 3);    // XCD swizzle
  u32 b  = id2 >> 7;
  u32 t  = (id2 >> 2) & 31;
  u32 r0 = (id2 & 3) * 8u;

  u32 tid = threadIdx.x;
  u32 lane = tid & 63, wave = tid >> 6;
  u32 wm = wave >> 2, wn = wave & 3;         // 2 x 4 wave grid

  const u16* xb = xt + (size_t)b * P3 * CIN;
  u32 pBase = ((t + 1) * PD + (r0 + 1)) * PD + 1;

  // staging source offsets. A chunk i: rows i*64+lane (natural order).
  // B slot s -> spatial row n(s): UB0 = slots 0-127 = rows with (n&32)==0.
  u32 aOff[4], bOffS[4];
#pragma unroll
  for (int i = 0; i < 4; ++i) {
    aOff[i] = (i * 64u + lane) * CIN + wave * 8u;
    u32 nRow = (lane & 31) + (((2u * i + (lane >> 5)) & 3u) * 64u) + ((u32)(i >> 1) * 32u);
    bOffS[i] = (pBase + (nRow >> 5) * PD + (nRow & 31)) * CIN + wave * 8u;
  }

  // A-unit IA=0 stages row-chunks {0,2} (rows 0-63,128-191: read at MH=0);
  // IA=1 -> chunks {1,3} (read at MH=1). B-unit I0=0 -> slots 0-127 (NH=0);
  // I0=2 -> slots 128-255 (NH=1).
#define STAGE_A(KU, IA) do {                                                  \
    u32 ku_ = (u32)(KU);                                                      \
    const u16* g_ = wb + (size_t)(ku_ >> 2) * (COUT * CIN) + (ku_ & 3u) * 64u;\
    gload_lds16(g_ + aOff[IA],       &lds[ku_ & 1u][0][wave][(IA) * 64][0]);  \
    gload_lds16(g_ + aOff[(IA) + 2], &lds[ku_ & 1u][0][wave][(IA) * 64 + 128][0]); \
  } while (0)

#define STAGE_B(KU, I0) do {                                                  \
    u32 ku_ = (u32)(KU);                                                      \
    const u16* g_ = xb + (ptrdiff_t)((int)((ku_ & 3u) * 64u)                  \
                                     + tapOff(ku_ >> 2) * (int)CIN);          \
    gload_lds16(g_ + bOffS[I0],       &lds[ku_ & 1u][1][wave][(I0) * 64][0]); \
    gload_lds16(g_ + bOffS[(I0) + 1], &lds[ku_ & 1u][1][wave][(I0) * 64 + 64][0]); \
  } while (0)

  f32x4 acc[8][4];
#pragma unroll
  for (int i = 0; i < 8; ++i)
#pragma unroll
    for (int j = 0; j < 4; ++j) acc[i][j] = (f32x4)0.0f;

  // phase body: read quadrant (MH,NH) frags, issue stage, barrier, MFMA.
#define PHASE(MH, NH, DOSTAGE) do {                                           \
    bf16x8 af[2][4], bv[2][2];                                                \
    _Pragma("unroll")                                                         \
    for (int ks = 0; ks < 2; ++ks) {                                          \
      _Pragma("unroll")                                                       \
      for (int mi = 0; mi < 4; ++mi)                                          \
        af[ks][mi] = *(const bf16x8*)&lds[buf][0][ks * 4 + (lane >> 4)]       \
            [wm * 128 + (MH) * 64 + mi * 16 + (lane & 15)][0];                \
      _Pragma("unroll")                                                       \
      for (int ni = 0; ni < 2; ++ni)                                          \
        bv[ks][ni] = *(const bf16x8*)&lds[buf][1][ks * 4 + (lane >> 4)]       \
            [(NH) * 128 + wn * 32 + ni * 16 + (lane & 15)][0];                \
    }                                                                         \
    DOSTAGE;                                                                  \
    __builtin_amdgcn_s_barrier();                                             \
    __builtin_amdgcn_sched_barrier(0);                                        \
    __builtin_amdgcn_s_setprio(1);                                            \
    _Pragma("unroll")                                                         \
    for (int ks = 0; ks < 2; ++ks)                                            \
      _Pragma("unroll")                                                       \
      for (int mi = 0; mi < 4; ++mi)                                          \
        _Pragma("unroll")                                                     \
        for (int ni = 0; ni < 2; ++ni)                                        \
          acc[(MH) * 4 + mi][(NH) * 2 + ni] =                                 \
              __builtin_amdgcn_mfma_f32_16x16x32_bf16(                        \
                  af[ks][mi], bv[ks][ni], acc[(MH) * 4 + mi][(NH) * 2 + ni],  \
                  0, 0, 0);                                                   \
    __builtin_amdgcn_s_setprio(0);                                            \
  } while (0)

  // prologue: tile0 all 4 units, then tile1 units UA0,UB1 -> vmcnt(4) = tile0 landed
  STAGE_A(0, 0); STAGE_B(0, 2); STAGE_A(0, 1); STAGE_B(0, 0);
  STAGE_A(1, 0); STAGE_B(1, 2);
  asm volatile("s_waitcnt vmcnt(4)" ::: "memory");
  __builtin_amdgcn_s_barrier();
  __builtin_amdgcn_sched_barrier(0);

#pragma unroll 1
  for (int kt = 0; kt < 28; ++kt) {
    u32 buf = kt & 1;
    // p0: quadrant (0,0); stage UA1 of kt+1 (into buf^1, write-only this tile)
    PHASE(0, 0, { if (kt + 1 < 28) STAGE_A(kt + 1, 1); });
    __builtin_amdgcn_s_barrier();
    __builtin_amdgcn_sched_barrier(0);
    // p1: quadrant (0,1); stage UB0 of kt+1
    PHASE(0, 1, { if (kt + 1 < 28) STAGE_B(kt + 1, 0); });
    __builtin_amdgcn_s_barrier();
    __builtin_amdgcn_sched_barrier(0);
    // p2: quadrant (1,1); stage UA0 of kt+2 (into buf: rows only read at p0/p1)
    PHASE(1, 1, { if (kt + 2 < 28) STAGE_A(kt + 2, 0); });
    __builtin_amdgcn_s_barrier();
    __builtin_amdgcn_sched_barrier(0);
    // p3: quadrant (1,0); stage UB1 of kt+2 (slots only read at p1/p2)
    PHASE(1, 0, { if (kt + 2 < 28) STAGE_B(kt + 2, 2); });
    if (kt < 26) asm volatile("s_waitcnt vmcnt(4)" ::: "memory");
    else         asm volatile("s_waitcnt vmcnt(0)" ::: "memory");
    __builtin_amdgcn_s_barrier();
    __builtin_amdgcn_sched_barrier(0);
  }

#undef PHASE
#undef STAGE_A
#undef STAGE_B

  // epilogue: D row = (lane>>4)*4 + reg (cout), col = lane&15 (spatial)
  u32 rowg = (lane >> 4) * 4u;
  u32 coln = lane & 15u;
  float* ob = out + (size_t)(b * COUT + wm * 128u) * SPAT + t * 1024u + r0 * 32u;
#pragma unroll
  for (int mi = 0; mi < 8; ++mi)
#pragma unroll
    for (int ni = 0; ni < 4; ++ni) {
      f32x4 v = acc[mi][ni];
      u32 n = wn * 64u + ni * 16u + coln;
#pragma unroll
      for (int rg = 0; rg < 4; ++rg)
        ob[(size_t)(mi * 16u + rowg + rg) * SPAT + n] = v[rg];
    }
}

extern "C" void kernel_launch(void* const* d_in, const int* in_sizes, int n_in,
                              void* d_out, int out_size, void* d_ws, size_t ws_size,
                              hipStream_t stream) {
  const float* x = (const float*)d_in[0];
  const float* W = (const float*)d_in[1];
  float* out = (float*)d_out;
  u16* xt  = (u16*)d_ws;
  u16* wbf = (u16*)((char*)d_ws + WB_OFF_BYTES);

  hipMemsetAsync(d_ws, 0, XT_BYTES, stream);
  hipLaunchKernelGGL(convert_w,     dim3(224),  dim3(256), 0, stream, W, wbf);
  hipLaunchKernelGGL(transpose_pad, dim3(2048), dim3(256), 0, stream, x, xt);
  hipLaunchKernelGGL(conv_main,     dim3(256),  dim3(512), 0, stream, xt, wbf, out);
}